// Round 11
// baseline (140.991 us; speedup 1.0000x reference)
//
#include <hip/hip_runtime.h>

#define NE 24
#define NB 8192
#define FIN 15
#define H1 512
#define H2 512
#define H3 256
#define TS 16
#define SLOTS 520            // worst-case tiles per XCD (8192/16 + partials)
#define GRIDM (8 * SLOTS)    // 4160 blocks, idle ones exit immediately
#define EPB 201              // pack blocks per expert (201*256 >= 51232 g-units)
#define PACKBLK (8 * 3 * EPB)  // 4824 pack blocks; block PACKBLK does planning

// ---- ws layout (int32 offsets) ----
#define WS_OFF 0      // [25]
#define WS_XN  32     // [8]
#define WS_XT  64     // [8*520] packed (e<<16)|tile
#define WS_ORD 8192   // [8192]
// bf16 region starts at byte 65536:
#define WB_BYTE 65536
#define OW1 0         // [24][4][512][8]
#define OW2 393216    // [24][64][512][8]
#define OW3 6684672   // [24][64][256][8]
#define OW4 9830400   // [24][256]

typedef __attribute__((ext_vector_type(8))) short short8v;
typedef __attribute__((ext_vector_type(4))) float f32x4;

__device__ __forceinline__ unsigned short f2bf(float x) {
  unsigned int u = __float_as_uint(x);
  unsigned int r = (u + 0x7fffu + ((u >> 16) & 1u)) >> 16;
  return (unsigned short)r;
}
__device__ __forceinline__ float bf2f(unsigned short h) {
  return __uint_as_float(((unsigned int)h) << 16);
}

// ---- fused pack + plan, XCD-co-located ----
// Pack blocks: bid = slot*8 + x (x = XCD). XCD x packs experts {x, x+8, x+16}
// so expert e's wb lines are dirty in XCD (e%8)'s L2 — the same XCD whose
// k_mlp blocks will read them.
__global__ __launch_bounds__(256) void k_pack(
    const float* __restrict__ W1, const float* __restrict__ W2,
    const float* __restrict__ W3, const float* __restrict__ W4,
    const int* __restrict__ midx, int* __restrict__ ws,
    unsigned short* __restrict__ wb) {
  const int t = threadIdx.x;
  if (blockIdx.x == PACKBLK) {
    __shared__ int hist[NE];
    __shared__ int off[NE + 1];
    __shared__ int cur[NE];
    __shared__ int tb[NE];
    __shared__ int xn[8];
    if (t < NE) hist[t] = 0;
    __syncthreads();
    int ev[32];
    #pragma unroll
    for (int r = 0; r < 32; ++r) {
      ev[r] = midx[r * 256 + t];
      atomicAdd(&hist[ev[r]], 1);
    }
    __syncthreads();
    if (t == 0) {
      int o = 0;
      #pragma unroll
      for (int i = 0; i < NE; ++i) { off[i] = o; cur[i] = o; o += hist[i]; }
      off[NE] = o;
    }
    if (t >= 32 && t < 40) {  // per-XCD tile-slot prefix, strided (no scratch)
      const int x = t - 32;
      int o = 0;
      for (int i = x; i < NE; i += 8) { tb[i] = o; o += (hist[i] + TS - 1) / TS; }
      xn[x] = o;
    }
    __syncthreads();
    if (t < NE + 1) ws[WS_OFF + t] = off[t];
    if (t >= 32 && t < 40) ws[WS_XN + t - 32] = xn[t - 32];
    for (int e = 0; e < NE; ++e) {
      const int nt = (hist[e] + TS - 1) / TS;
      for (int k = t; k < nt; k += 256)
        ws[WS_XT + (e & 7) * SLOTS + tb[e] + k] = (e << 16) | k;
    }
    #pragma unroll
    for (int r = 0; r < 32; ++r) {
      const int p = atomicAdd(&cur[ev[r]], 1);
      ws[WS_ORD + p] = r * 256 + t;
    }
    return;
  }
  // pack path: per-expert g-units: W1 [0,2048) W2 [2048,34816) W3 [34816,51200) W4 [51200,51232)
  const int x = blockIdx.x & 7;
  const int s = blockIdx.x >> 3;
  const int e = x + 8 * (s / EPB);
  const int gl = (s % EPB) * 256 + t;
  if (gl >= 51232) return;
  const float* src;
  int kb, n, N, KR;
  size_t dsto;
  if (gl < 2048) {
    kb = gl >> 9; n = gl & 511; N = 512; KR = FIN;
    src = W1 + (size_t)e * FIN * 512;
    dsto = OW1 + ((size_t)e * 2048 + gl) * 8;
  } else if (gl < 34816) {
    const int g2 = gl - 2048;
    kb = g2 >> 9; n = g2 & 511; N = 512; KR = 512;
    src = W2 + (size_t)e * 512 * 512;
    dsto = OW2 + ((size_t)e * 32768 + g2) * 8;
  } else if (gl < 51200) {
    const int g3 = gl - 34816;
    kb = g3 >> 8; n = g3 & 255; N = 256; KR = 512;
    src = W3 + (size_t)e * 512 * 256;
    dsto = OW3 + ((size_t)e * 16384 + g3) * 8;
  } else {
    const int g4 = gl - 51200;
    kb = g4; n = 0; N = 1; KR = 256;
    src = W4 + (size_t)e * 256;
    dsto = OW4 + (size_t)e * 256 + (size_t)g4 * 8;
  }
  short8v v;
  #pragma unroll
  for (int j = 0; j < 8; ++j) {
    const int k = kb * 8 + j;
    const float f = (k < KR) ? src[(size_t)k * N + n] : 0.f;
    v[j] = (short)f2bf(f);
  }
  *(short8v*)(wb + dsto) = v;
}

// MFMA layer, depth-3 rotating B prefetch over 4 buffers:
// (ks+3)&3 != ks&3, so the prefetch never clobbers the slice being consumed
// (R9 bug: depth-4 over 4 buffers aliased). Full unroll -> static indices.
// A in LDS [KS*4][TS][8], B global [KS*4][N][8], fp32 bias, relu,
// bf16 out to LDS [N/8][TS][8].
template <int NT, int KS>
__device__ __forceinline__ void layer_gemm(const unsigned short* __restrict__ aLDS,
                                           const unsigned short* __restrict__ bGlob,
                                           const float* __restrict__ bias,
                                           unsigned short* __restrict__ dLDS,
                                           int N, int ncol0, int lr, int lc) {
  f32x4 acc[NT];
  #pragma unroll
  for (int nt = 0; nt < NT; ++nt) acc[nt] = (f32x4){0.f, 0.f, 0.f, 0.f};

  const unsigned short* bbase = bGlob + ((size_t)lc * N + ncol0 + lr) * 8;
  const size_t kstep = (size_t)4 * N * 8;  // one slice = 4 k-rows

  short8v bb[4][NT];
  #pragma unroll
  for (int p = 0; p < 3; ++p) {
    if (p < KS) {
      #pragma unroll
      for (int nt = 0; nt < NT; ++nt)
        bb[p][nt] = *(const short8v*)(bbase + p * kstep + nt * 128);
    }
  }
  #pragma unroll
  for (int ks = 0; ks < KS; ++ks) {
    if (ks + 3 < KS) {
      #pragma unroll
      for (int nt = 0; nt < NT; ++nt)
        bb[(ks + 3) & 3][nt] = *(const short8v*)(bbase + (ks + 3) * kstep + nt * 128);
    }
    const short8v a = *(const short8v*)(aLDS + (((ks * 4 + lc) * TS) + lr) * 8);
    #pragma unroll
    for (int nt = 0; nt < NT; ++nt)
      acc[nt] = __builtin_amdgcn_mfma_f32_16x16x32_bf16(a, bb[ks & 3][nt], acc[nt], 0, 0, 0);
  }
  #pragma unroll
  for (int nt = 0; nt < NT; ++nt) {
    const int col = ncol0 + nt * 16 + lr;
    const float bv = bias[col];
    #pragma unroll
    for (int j = 0; j < 4; ++j) {
      const int row = lc * 4 + j;
      const float v = fmaxf(acc[nt][j] + bv, 0.f);
      dLDS[(((col >> 3) * TS) + row) * 8 + (col & 7)] = f2bf(v);
    }
  }
}

__global__ __launch_bounds__(512, 4) void k_mlp(
    const float* __restrict__ features,
    const float* __restrict__ b1, const float* __restrict__ b2,
    const float* __restrict__ b3, const float* __restrict__ b4,
    const int* __restrict__ ws, const unsigned short* __restrict__ wb,
    float* __restrict__ out) {
  __shared__ int sidx[TS];
  __shared__ __align__(16) unsigned short fA[4][TS][8];     // 1 KB
  __shared__ __align__(16) unsigned short actA[64][TS][8];  // 16 KB
  __shared__ __align__(16) unsigned short actB[64][TS][8];  // 16 KB

  const int t = threadIdx.x;
  const int wv = t >> 6;   // 0..7
  const int ln = t & 63;
  const int lr = ln & 15;
  const int lc = ln >> 4;

  const int bid = blockIdx.x;
  const int xcd = bid & 7;
  const int slot = bid >> 3;
  if (slot >= ws[WS_XN + xcd]) return;  // block-uniform
  const int packed = ws[WS_XT + xcd * SLOTS + slot];
  const int e = packed >> 16;
  const int tt = packed & 0xffff;
  const int start = ws[WS_OFF + e] + tt * TS;
  const int cnt = min(TS, ws[WS_OFF + e + 1] - start);

  if (t < TS) sidx[t] = (t < cnt) ? ws[WS_ORD + start + t] : ws[WS_ORD + start];
  __syncthreads();

  if (t < 64) {  // stage features as A-fragments (K padded to 32)
    int m = t >> 2, cb = t & 3;
    #pragma unroll
    for (int j = 0; j < 8; ++j) {
      int k = cb * 8 + j;
      fA[cb][m][j] = (k < FIN) ? f2bf(features[(size_t)sidx[m] * FIN + k]) : 0;
    }
  }
  __syncthreads();

  const unsigned short* w1p = wb + OW1 + (size_t)e * 4 * 512 * 8;
  const unsigned short* w2p = wb + OW2 + (size_t)e * 64 * 512 * 8;
  const unsigned short* w3p = wb + OW3 + (size_t)e * 64 * 256 * 8;
  const unsigned short* w4p = wb + OW4 + (size_t)e * 256;

  layer_gemm<4, 1>(&fA[0][0][0], w1p, b1 + e * H1, &actA[0][0][0], 512, wv * 64, lr, lc);
  __syncthreads();
  layer_gemm<4, 16>(&actA[0][0][0], w2p, b2 + e * H2, &actB[0][0][0], 512, wv * 64, lr, lc);
  __syncthreads();
  layer_gemm<2, 16>(&actB[0][0][0], w3p, b3 + e * H3, &actA[0][0][0], 256, wv * 32, lr, lc);
  __syncthreads();

  // layer 4: out[m] = h3[m][:] . W4 + b4, 8 threads per sample
  if (t < 128) {
    int m = t >> 3, c = t & 7;
    float p = 0.f;
    #pragma unroll
    for (int kk = 0; kk < 32; ++kk)
      p += bf2f(actA[0][0][(kk * TS + m) * 8 + c]) * bf2f(w4p[kk * 8 + c]);
    p += __shfl_xor(p, 1);
    p += __shfl_xor(p, 2);
    p += __shfl_xor(p, 4);
    if (c == 0 && m < cnt) out[sidx[m]] = p + b4[e];
  }
}

extern "C" void kernel_launch(void* const* d_in, const int* in_sizes, int n_in,
                              void* d_out, int out_size, void* d_ws, size_t ws_size,
                              hipStream_t stream) {
  const float* features = (const float*)d_in[0];
  const int* midx = (const int*)d_in[1];
  const float* W1 = (const float*)d_in[2];
  const float* b1 = (const float*)d_in[3];
  const float* W2 = (const float*)d_in[4];
  const float* b2 = (const float*)d_in[5];
  const float* W3 = (const float*)d_in[6];
  const float* b3 = (const float*)d_in[7];
  const float* W4 = (const float*)d_in[8];
  const float* b4 = (const float*)d_in[9];
  int* ws = (int*)d_ws;
  unsigned short* wb = (unsigned short*)((char*)d_ws + WB_BYTE);
  float* out = (float*)d_out;

  k_pack<<<PACKBLK + 1, 256, 0, stream>>>(W1, W2, W3, W4, midx, ws, wb);
  k_mlp<<<GRIDM, 512, 0, stream>>>(features, b1, b2, b3, b4, ws, wb, out);
}